// Round 2
// baseline (516.313 us; speedup 1.0000x reference)
//
#include <hip/hip_runtime.h>
#include <hip/hip_bf16.h>

typedef __bf16 bf16x8 __attribute__((ext_vector_type(8)));
typedef float f32x4 __attribute__((ext_vector_type(4)));

#define D 128           // D_IN == D_OUT == 128
#define EDIM 16

__device__ inline unsigned short f2bf(float f) {   // RTNE fp32 -> bf16
    unsigned u = __builtin_bit_cast(unsigned, f);
    u += 0x7fffu + ((u >> 16) & 1u);
    return (unsigned short)(u >> 16);
}

// ---------------------------------------------------------------------------
// Kernel 0: out[m][j] = b[j]  (the edge kernel then accumulates on top;
// this replaces a separate acc buffer + finalize pass)
// ---------------------------------------------------------------------------
__global__ __launch_bounds__(256) void init_out(
    float* __restrict__ out, const float* __restrict__ b, long total4)
{
    const long i = (long)blockIdx.x * 256 + threadIdx.x;
    if (i >= total4) return;
    ((float4*)out)[i] = ((const float4*)b)[(int)(i & 31)];   // (i*4)%128 / 4
}

// ---------------------------------------------------------------------------
// Kernel 1: xw = x @ W  (fp32 inputs, on-the-fly bf16 convert, MFMA 16x16x32,
// fp32 accumulate). Block = 256 = 4 waves; wave w owns cols [32w, 32w+32).
// W staged TRANSPOSED as bf16 in LDS (row stride 136 shorts, 16B aligned)
// so the B-fragment is one contiguous ds_read_b128.
// ---------------------------------------------------------------------------
__global__ __launch_bounds__(256) void gemm_xw(
    const float* __restrict__ x,   // [N,128] fp32
    const float* __restrict__ W,   // [128,128] fp32
    float* __restrict__ xw,        // [N,128] fp32
    int ntiles)
{
    __shared__ unsigned short Wt[128][136];
    const int t = threadIdx.x;

    #pragma unroll
    for (int i = 0; i < 16; ++i) {
        int id = (i * 256 + t) * 4;            // 4 consecutive n at row k
        float4 p = *(const float4*)(W + id);
        int k = id >> 7, n = id & 127;
        Wt[n + 0][k] = f2bf(p.x);
        Wt[n + 1][k] = f2bf(p.y);
        Wt[n + 2][k] = f2bf(p.z);
        Wt[n + 3][k] = f2bf(p.w);
    }
    __syncthreads();

    const int wave = t >> 6, lane = t & 63;
    const int quad = lane >> 4, low = lane & 15;
    const int n0 = wave * 32;

    for (int mt = blockIdx.x; mt < ntiles; mt += gridDim.x) {
        const int arow = mt * 16 + low;
        f32x4 acc0 = {0.f, 0.f, 0.f, 0.f};
        f32x4 acc1 = {0.f, 0.f, 0.f, 0.f};
        #pragma unroll
        for (int kc = 0; kc < 4; ++kc) {
            const int k0 = kc * 32 + quad * 8;
            const float* xp = x + (size_t)arow * D + k0;
            float4 a0 = *(const float4*)xp;
            float4 a1 = *(const float4*)(xp + 4);
            union { unsigned short us[8]; bf16x8 v; } a;
            a.us[0] = f2bf(a0.x); a.us[1] = f2bf(a0.y);
            a.us[2] = f2bf(a0.z); a.us[3] = f2bf(a0.w);
            a.us[4] = f2bf(a1.x); a.us[5] = f2bf(a1.y);
            a.us[6] = f2bf(a1.z); a.us[7] = f2bf(a1.w);
            bf16x8 b0 = *(const bf16x8*)(&Wt[n0 + low][k0]);
            bf16x8 b1 = *(const bf16x8*)(&Wt[n0 + 16 + low][k0]);
            acc0 = __builtin_amdgcn_mfma_f32_16x16x32_bf16(a.v, b0, acc0, 0, 0, 0);
            acc1 = __builtin_amdgcn_mfma_f32_16x16x32_bf16(a.v, b1, acc1, 0, 0, 0);
        }
        // C/D: col = lane&15, row = quad*4 + reg
        #pragma unroll
        for (int r = 0; r < 4; ++r) {
            const size_t row = (size_t)mt * 16 + quad * 4 + r;
            xw[row * D + n0 + low]      = acc0[r];
            xw[row * D + n0 + 16 + low] = acc1[r];
        }
    }
}

// ---------------------------------------------------------------------------
// Kernel 2: for each edge e: out[dst] += xw[src] * (ea[e] @ edge_w)
// 256 threads: channel j = t&127 fixed per thread -> edge_w column hoisted
// into 16 registers. Two edges in flight per iteration (t>>7).
// Scatter via HW fp32 atomics (global_atomic_add_f32).
// ---------------------------------------------------------------------------
__global__ __launch_bounds__(256) void edge_kernel(
    const int* __restrict__ ei,    // [2,E] int32
    const float* __restrict__ ea,  // [E,16] fp32
    const float* __restrict__ ew,  // [16,128] fp32
    const float* __restrict__ xw,  // [N,128] fp32
    float* __restrict__ out,       // [N,128] fp32 (pre-filled with b)
    int E, int epb)
{
    __shared__ float ewT[128][20];       // ewT[j][k], 80B rows (16B aligned)
    const int t = threadIdx.x;
    for (int id = t; id < EDIM * D; id += 256) {
        ewT[id & 127][id >> 7] = ew[id]; // id: k = id>>7, j = id&127
    }
    __syncthreads();

    const int j = t & 127, half = t >> 7;
    const float4* wr = (const float4*)&ewT[j][0];
    const float4 c0 = wr[0], c1 = wr[1], c2 = wr[2], c3 = wr[3];

    const long base = (long)blockIdx.x * epb;
    for (int it = 0; it < epb; it += 2) {
        const long e = base + it + half;
        if (e < E) {
            const int src = ei[e];
            const int dst = ei[(long)E + e];
            const float4* eap = (const float4*)(ea + e * EDIM);
            const float4 p0 = eap[0], p1 = eap[1], p2 = eap[2], p3 = eap[3];

            float s;
            s  = p0.x * c0.x + p0.y * c0.y + p0.z * c0.z + p0.w * c0.w;
            s += p1.x * c1.x + p1.y * c1.y + p1.z * c1.z + p1.w * c1.w;
            s += p2.x * c2.x + p2.y * c2.y + p2.z * c2.z + p2.w * c2.w;
            s += p3.x * c3.x + p3.y * c3.y + p3.z * c3.z + p3.w * c3.w;

            const float xwv = xw[(size_t)src * D + j];
            unsafeAtomicAdd(&out[(size_t)dst * D + j], xwv * s);
        }
    }
}

extern "C" void kernel_launch(void* const* d_in, const int* in_sizes, int n_in,
                              void* d_out, int out_size, void* d_ws, size_t ws_size,
                              hipStream_t stream) {
    const float* x  = (const float*)d_in[0];
    const int*   ei = (const int*)d_in[1];
    const float* ea = (const float*)d_in[2];
    const float* W  = (const float*)d_in[3];
    const float* ew = (const float*)d_in[4];
    const float* bb = (const float*)d_in[5];
    float* out = (float*)d_out;

    const int N = in_sizes[0] / D;        // 100000
    const int E = in_sizes[2] / EDIM;     // 800000

    float* xw = (float*)d_ws;             // [N,128] fp32 (51.2 MB)

    const long total4 = (long)N * D / 4;
    init_out<<<(int)((total4 + 255) / 256), 256, 0, stream>>>(out, bb, total4);

    const int ntiles = N / 16;            // 6250 exact
    gemm_xw<<<1024, 256, 0, stream>>>(x, W, xw, ntiles);

    const int epb = 32;                   // edges per block
    edge_kernel<<<(E + epb - 1) / epb, 256, 0, stream>>>(ei, ea, ew, xw, out, E, epb);
}